// Round 3
// baseline (767.313 us; speedup 1.0000x reference)
//
#include <hip/hip_runtime.h>
#include <hip/hip_fp16.h>
#include <cstdint>
#include <cstddef>

// Problem constants (hardcoded per reference setup_inputs)
#define B_    4
#define Q_    8192
#define E_    256
#define H_    8
#define L_    4
#define P_    4
#define HD_   32
#define VLEN_ 21760   // 128^2 + 64^2 + 32^2 + 16^2
#define K_    256
#define VROW_ 170     // 128-row tiles per batch in vproj (170*128 = 21760)
#define QBLK_ (Q_ / 16)      // 512 query-tiles per batch in fused

__device__ inline unsigned pk2(float a, float b) {
  __half2 h = __floats2half2_rn(a, b);
  union { __half2 h2; unsigned u; } cv; cv.h2 = h; return cv.u;
}

// ---------------- Kernel 1: value projection -> fp16, head-major ----------------
// v16[h][pix][c] (c in 0..31 halves) = sum_k value[pix][k] * V_W[h*32+c][k].
// 128x128 tile per block, 8x8 per-thread fragments split 4+4 (conflict-free).
__global__ __launch_bounds__(256)
void gemm_vproj(const float* __restrict__ A,      // value (batch 0 base)
                const float* __restrict__ W,      // V_W (256,256)
                __half* __restrict__ C16,         // v16
                size_t a_bstride, size_t c_bstride)  // c_bstride in halves
{
  // k-major chunk tiles: [kk][row], row-stride 132 floats:
  //  - 132*4 = 528 B, 16B-aligned rows (b128 ok)
  //  - 4 rows apart = 528 floats = 16 mod 32 banks -> staging writes 2-way (free)
  __shared__ float Ak[16][132];
  __shared__ float Wk[16][132];

  const int t  = threadIdx.x;
  const int tx = t & 15, ty = t >> 4;
  const int b  = blockIdx.x / VROW_;
  const int bm = blockIdx.x - b * VROW_;
  const int bn = blockIdx.y;               // 0..1 (two 128-col halves)

  A   += (size_t)b * a_bstride;
  C16 += (size_t)b * c_bstride;

  float acc[8][8] = {};   // row r: gm = bm*128+(r>>2)*64+ty*4+(r&3); col c: gn = bn*128+(c>>2)*64+tx*4+(c&3)

  for (int k0 = 0; k0 < K_; k0 += 16) {
    __syncthreads();
#pragma unroll
    for (int i2 = 0; i2 < 2; ++i2) {
      const int idx = t + 256 * i2;        // 0..511
      const int row = idx >> 2;            // 0..127
      const int kq4 = (idx & 3) * 4;
      const float4 va = *(const float4*)(A + (size_t)(bm * 128 + row) * K_ + k0 + kq4);
      Ak[kq4+0][row] = va.x; Ak[kq4+1][row] = va.y; Ak[kq4+2][row] = va.z; Ak[kq4+3][row] = va.w;
      const float4 vw = *(const float4*)(W + (size_t)(bn * 128 + row) * K_ + k0 + kq4);
      Wk[kq4+0][row] = vw.x; Wk[kq4+1][row] = vw.y; Wk[kq4+2][row] = vw.z; Wk[kq4+3][row] = vw.w;
    }
    __syncthreads();
#pragma unroll
    for (int kk = 0; kk < 16; ++kk) {
      const float4 a0 = *(const float4*)&Ak[kk][ty * 4];
      const float4 a1 = *(const float4*)&Ak[kk][64 + ty * 4];
      const float4 w0 = *(const float4*)&Wk[kk][tx * 4];
      const float4 w1 = *(const float4*)&Wk[kk][64 + tx * 4];
      const float av[8] = {a0.x, a0.y, a0.z, a0.w, a1.x, a1.y, a1.z, a1.w};
      const float wv[8] = {w0.x, w0.y, w0.z, w0.w, w1.x, w1.y, w1.z, w1.w};
#pragma unroll
      for (int r = 0; r < 8; ++r)
#pragma unroll
        for (int c = 0; c < 8; ++c)
          acc[r][c] += av[r] * wv[c];
    }
  }

  // epilogue: fp16 stores, head-major layout [h][pix][32]
#pragma unroll
  for (int r = 0; r < 8; ++r) {
    const int gm = bm * 128 + (r >> 2) * 64 + ty * 4 + (r & 3);
#pragma unroll
    for (int cg = 0; cg < 2; ++cg) {
      const int gn0 = bn * 128 + cg * 64 + tx * 4;     // 4 contiguous channels, within one head
      const int h  = gn0 >> 5;
      const int c0 = gn0 & 31;
      __half* dst = C16 + ((size_t)h * VLEN_ + gm) * 32 + c0;
      uint2 sv;
      sv.x = pk2(acc[r][cg * 4 + 0], acc[r][cg * 4 + 1]);
      sv.y = pk2(acc[r][cg * 4 + 2], acc[r][cg * 4 + 3]);
      *(uint2*)dst = sv;
    }
  }
}

// ---------------- Kernel 2: fused offsets/attn GEMM + softmax + sampling ----------------
// One block = 16 consecutive queries of one batch. Single K-loop GEMM: each
// thread owns cols {lane*4..+3} (offsets) + {256+lane*2, +1} (attn) -> one
// ds_read_b128 + one ds_read_b64 per k. x/y offset pairs are thread-local.
// Gather reads fp16 v16 (head-major) with fp32 accumulate (v_fma_mix).
__global__ __launch_bounds__(256)
void fused_offattn_sample(const float* __restrict__ queries,
                          const float* __restrict__ ref_points,
                          const float* __restrict__ off_W,
                          const float* __restrict__ off_b,
                          const float* __restrict__ attn_W,
                          const float* __restrict__ attn_b,
                          const __half* __restrict__ v16,
                          float* __restrict__ outpre,
                          size_t q_bstride, size_t r_bstride,
                          size_t v_bstride, size_t o_bstride)   // v_bstride in halves
{
  __shared__ float qs[16][260];            // query tile fp32 (pad 4, rows 16B-aligned)
  __shared__ float upool[16 * 388];        // union: wck[16][388] | {s_px,s_py,s_a}[16][128]
  __shared__ float refs[16][8];            // ref_points per query (l, xy)
  __shared__ int4   s_idx4[2][128];        // 4 bilinear pixel indices per tap, 2 queries
  __shared__ float4 s_w4[2][128];          // 4 combined weights (attn*bilinear) per tap

  float (*wck)[388]  = (float (*)[388])upool;
  float (*s_px)[128] = (float (*)[128])upool;              // floats [0, 2048)
  float (*s_py)[128] = (float (*)[128])(upool + 16 * 128); // [2048, 4096)
  float (*s_a)[128]  = (float (*)[128])(upool + 32 * 128); // [4096, 6144)

  const int t     = threadIdx.x;
  const int lane  = t & 63;
  const int wv    = t >> 6;                // wave id: q rows {wv, wv+4, wv+8, wv+12}
  const int b     = blockIdx.x >> 9;       // batch (0 when grid is per-batch)
  const int qbase = (blockIdx.x & (QBLK_ - 1)) * 16;

  queries    += (size_t)b * q_bstride;
  ref_points += (size_t)b * r_bstride;
  outpre     += (size_t)b * o_bstride;
  const __half* v16b = v16 + (size_t)b * v_bstride;

  // ---- load query tile + ref points
  {
    const int r  = t >> 4;
    const int c0 = (t & 15) * 16;
    const float4* src = (const float4*)(queries + (size_t)(qbase + r) * K_ + c0);
    *(float4*)&qs[r][c0 + 0]  = src[0];
    *(float4*)&qs[r][c0 + 4]  = src[1];
    *(float4*)&qs[r][c0 + 8]  = src[2];
    *(float4*)&qs[r][c0 + 12] = src[3];
  }
  if (t < 128) refs[t >> 3][t & 7] = ref_points[(size_t)(qbase + (t >> 3)) * 8 + (t & 7)];

  // ---- precompute weight-staging sources: 1536 float4 per chunk, 6 per thread
  const float* wsrc[6]; int wcol[6]; int wm4[6];
#pragma unroll
  for (int n = 0; n < 6; ++n) {
    const int e   = n * 256 + t;           // 0..1535
    const int col = e % 384;               // output column
    const int m   = e / 384;               // k-subgroup (0..3)
    wcol[n] = col; wm4[n] = m * 4;
    wsrc[n] = (col < 256 ? off_W + (size_t)col * K_
                         : attn_W + (size_t)(col - 256) * K_) + m * 4;
  }

  float acc0[4][4] = {};   // offset cols lane*4+j, q rows wv+4i
  float acc1[2][4] = {};   // attn cols 256+lane*2+u2

  for (int k0 = 0; k0 < K_; k0 += 16) {
    __syncthreads();
#pragma unroll
    for (int n = 0; n < 6; ++n) {
      const float4 v = *(const float4*)(wsrc[n] + k0);
      wck[wm4[n] + 0][wcol[n]] = v.x;
      wck[wm4[n] + 1][wcol[n]] = v.y;
      wck[wm4[n] + 2][wcol[n]] = v.z;
      wck[wm4[n] + 3][wcol[n]] = v.w;
    }
    __syncthreads();
#pragma unroll
    for (int kc = 0; kc < 4; ++kc) {
      const float4 qv0 = *(const float4*)&qs[wv +  0][k0 + kc * 4];
      const float4 qv1 = *(const float4*)&qs[wv +  4][k0 + kc * 4];
      const float4 qv2 = *(const float4*)&qs[wv +  8][k0 + kc * 4];
      const float4 qv3 = *(const float4*)&qs[wv + 12][k0 + kc * 4];
      const float* q0 = (const float*)&qv0; const float* q1 = (const float*)&qv1;
      const float* q2 = (const float*)&qv2; const float* q3 = (const float*)&qv3;
#pragma unroll
      for (int s = 0; s < 4; ++s) {
        const int kk = kc * 4 + s;
        const float4 w4 = *(const float4*)&wck[kk][lane * 4];
        const float2 w2 = *(const float2*)&wck[kk][256 + lane * 2];
        const float qk[4] = {q0[s], q1[s], q2[s], q3[s]};
#pragma unroll
        for (int i = 0; i < 4; ++i) {
          acc0[0][i] += w4.x * qk[i]; acc0[1][i] += w4.y * qk[i];
          acc0[2][i] += w4.z * qk[i]; acc0[3][i] += w4.w * qk[i];
          acc1[0][i] += w2.x * qk[i]; acc1[1][i] += w2.y * qk[i];
        }
      }
    }
  }
  __syncthreads();   // wck dead from here; upool becomes s_px/s_py/s_a

  // ---- offsets epilogue: thread owns cols lane*4..+3 = taps lane*2, lane*2+1 (x,y local)
  {
    const int l  = (lane >> 1) & 3;
    const int Wl = 128 >> l;
    const float sc = 0.5f * (float)(Wl - 1);
#pragma unroll
    for (int j2 = 0; j2 < 2; ++j2) {
      const int colx = lane * 4 + j2 * 2;
      const int tap  = lane * 2 + j2;           // h*16 + l*4 + p
      const float bx = off_b[colx], by = off_b[colx + 1];
#pragma unroll
      for (int i = 0; i < 4; ++i) {
        const int q = wv + 4 * i;
        float lx = refs[q][l * 2 + 0] + tanhf(acc0[j2 * 2 + 0][i] + bx);  // OFFSET_SCALE=1
        float ly = refs[q][l * 2 + 1] + tanhf(acc0[j2 * 2 + 1][i] + by);
        lx = fminf(fmaxf(lx, -1.f), 1.f);
        ly = fminf(fmaxf(ly, -1.f), 1.f);
        s_px[q][tap] = (lx + 1.f) * sc;
        s_py[q][tap] = (ly + 1.f) * sc;
      }
    }
  }

  // ---- attention epilogue: thread owns logits lane*2, lane*2+1; head group = 8 lanes
  {
    const float ab0 = attn_b[lane * 2], ab1 = attn_b[lane * 2 + 1];
#pragma unroll
    for (int i = 0; i < 4; ++i) {
      const int q = wv + 4 * i;
      const float l0 = acc1[0][i] + ab0;
      const float l1 = acc1[1][i] + ab1;
      float m = fmaxf(l0, l1);
#pragma unroll
      for (int msk = 1; msk < 8; msk <<= 1) m = fmaxf(m, __shfl_xor(m, msk));
      const float e0 = __expf(l0 - m), e1 = __expf(l1 - m);
      float s = e0 + e1;
#pragma unroll
      for (int msk = 1; msk < 8; msk <<= 1) s += __shfl_xor(s, msk);
      s_a[q][lane * 2 + 0] = e0 / s;
      s_a[q][lane * 2 + 1] = e1 / s;
    }
  }

  // ---- sampling: 8 query-pairs; fp16 gather, fp32 accumulate
  const int c4 = t & 3;           // 16B group within the 64B head-slice
  const int j3 = (t >> 2) & 7;    // tap-slot (reduced via shuffles ^4,^8,^16)
  const int h  = t >> 5;          // head
  const float4* vb4 = (const float4*)v16b + (size_t)h * (VLEN_ * 4) + c4;  // slice = 4 float4

  for (int qp = 0; qp < 8; ++qp) {
    __syncthreads();              // s_idx4/s_w4 free; also orders epilogue writes (qp=0)
    {
      const int u  = t >> 7;      // which query of the pair
      const int g  = t & 127;     // tap index h*16 + l*4 + p
      const int qq = qp * 2 + u;
      const float a = s_a[qq][g];
      const int l  = (g >> 2) & 3;
      const int Wl = 128 >> l;
      const int base = (l == 0) ? 0 : (l == 1) ? 16384 : (l == 2) ? 20480 : 21504;
      const float x = s_px[qq][g], y = s_py[qq][g];
      const float x0f = floorf(x), y0f = floorf(y);
      const float wx = x - x0f, wy = y - y0f;
      const int x0 = min(max((int)x0f, 0), Wl - 1);
      const int x1 = min(x0 + 1, Wl - 1);
      const int y0 = min(max((int)y0f, 0), Wl - 1);
      const int y1 = min(y0 + 1, Wl - 1);
      s_idx4[u][g] = make_int4(base + y0 * Wl + x0, base + y0 * Wl + x1,
                               base + y1 * Wl + x0, base + y1 * Wl + x1);
      s_w4[u][g] = make_float4(a * (1.f - wy) * (1.f - wx), a * (1.f - wy) * wx,
                               a * wy * (1.f - wx),          a * wy * wx);
    }
    __syncthreads();
#pragma unroll
    for (int u = 0; u < 2; ++u) {
      float o[8] = {0.f, 0.f, 0.f, 0.f, 0.f, 0.f, 0.f, 0.f};
#pragma unroll
      for (int jj = 0; jj < 2; ++jj) {
        const int g = h * 16 + jj * 8 + j3;
        const int4   id = s_idx4[u][g];
        const float4 w  = s_w4[u][g];
        const float4 r0 = vb4[(size_t)id.x * 4];
        const float4 r1 = vb4[(size_t)id.y * 4];
        const float4 r2 = vb4[(size_t)id.z * 4];
        const float4 r3 = vb4[(size_t)id.w * 4];
        const __half2* p0 = (const __half2*)&r0;
        const __half2* p1 = (const __half2*)&r1;
        const __half2* p2 = (const __half2*)&r2;
        const __half2* p3 = (const __half2*)&r3;
#pragma unroll
        for (int c = 0; c < 4; ++c) {
          o[2*c+0] += w.x * __low2float(p0[c])  + w.y * __low2float(p1[c])
                    + w.z * __low2float(p2[c])  + w.w * __low2float(p3[c]);
          o[2*c+1] += w.x * __high2float(p0[c]) + w.y * __high2float(p1[c])
                    + w.z * __high2float(p2[c]) + w.w * __high2float(p3[c]);
        }
      }
      // reduce over j3 (lanes ^4, ^8, ^16 share h and c4)
#pragma unroll
      for (int msk = 4; msk <= 16; msk <<= 1)
#pragma unroll
        for (int c = 0; c < 8; ++c) o[c] += __shfl_xor(o[c], msk);
      if (j3 == 0) {
        float* dst = outpre + (size_t)(qbase + qp * 2 + u) * 256 + h * 32 + c4 * 8;
        *(float4*)dst       = make_float4(o[0], o[1], o[2], o[3]);
        *(float4*)(dst + 4) = make_float4(o[4], o[5], o[6], o[7]);
      }
    }
  }
}

// ---------------- Kernel 3: in-place output projection (fp32, race-free) ----------------
#define OSTEP(q, COMP) { \
  const float4 w = *(const float4*)&Wk[kc*4+(q)][tx*4]; \
  acc[0][0]+=a0.COMP*w.x; acc[0][1]+=a0.COMP*w.y; acc[0][2]+=a0.COMP*w.z; acc[0][3]+=a0.COMP*w.w; \
  acc[1][0]+=a1.COMP*w.x; acc[1][1]+=a1.COMP*w.y; acc[1][2]+=a1.COMP*w.z; acc[1][3]+=a1.COMP*w.w; \
  acc[2][0]+=a2.COMP*w.x; acc[2][1]+=a2.COMP*w.y; acc[2][2]+=a2.COMP*w.z; acc[2][3]+=a2.COMP*w.w; \
  acc[3][0]+=a3.COMP*w.x; acc[3][1]+=a3.COMP*w.y; acc[3][2]+=a3.COMP*w.z; acc[3][3]+=a3.COMP*w.w; }

__global__ __launch_bounds__(256)
void gemm_out_inplace(float* __restrict__ D,       // d_out (32768,256) fp32
                      const float* __restrict__ Wout)
{
  __shared__ float As[64][260];   // padded: stride 1040 B (16B-aligned, banks +4/row)
  __shared__ float Wk[16][68];    // k-major weight chunk

  const int t  = threadIdx.x;
  const int tx = t & 15, ty = t >> 4;
  const int bm = blockIdx.x;
  const int lr  = t >> 2;
  const int lc4 = (t & 3) * 4;

  // cache this block's 64 rows (16384 floats = 4096 float4)
#pragma unroll
  for (int i = 0; i < 16; ++i) {
    const int e = t + i * 256;               // float4 index 0..4095
    const int r = e >> 6, cc = e & 63;
    *(float4*)&As[r][cc * 4] = *(const float4*)(D + (size_t)(bm * 64 + r) * 256 + cc * 4);
  }

  for (int bn = 0; bn < 4; ++bn) {
    float acc[4][4] = {};
    for (int k0 = 0; k0 < K_; k0 += 16) {
      __syncthreads();   // protect Wk (and As on first iter) before rewrite
      {
        const float4 vw = *(const float4*)(Wout + (size_t)(bn * 64 + lr) * K_ + k0 + lc4);
        Wk[lc4+0][lr] = vw.x; Wk[lc4+1][lr] = vw.y; Wk[lc4+2][lr] = vw.z; Wk[lc4+3][lr] = vw.w;
      }
      __syncthreads();
#pragma unroll
      for (int kc = 0; kc < 4; ++kc) {
        const float4 a0 = *(const float4*)&As[ty * 4 + 0][k0 + kc * 4];
        const float4 a1 = *(const float4*)&As[ty * 4 + 1][k0 + kc * 4];
        const float4 a2 = *(const float4*)&As[ty * 4 + 2][k0 + kc * 4];
        const float4 a3 = *(const float4*)&As[ty * 4 + 3][k0 + kc * 4];
        OSTEP(0, x) OSTEP(1, y) OSTEP(2, z) OSTEP(3, w)
      }
    }
#pragma unroll
    for (int i = 0; i < 4; ++i)
#pragma unroll
      for (int j = 0; j < 4; ++j) {
        const int gm = bm * 64 + ty * 4 + i;
        const int gn = bn * 64 + tx * 4 + j;
        D[(size_t)gm * 256 + gn] = acc[i][j];    // own rows; As is a private copy
      }
  }
}

extern "C" void kernel_launch(void* const* d_in, const int* in_sizes, int n_in,
                              void* d_out, int out_size, void* d_ws, size_t ws_size,
                              hipStream_t stream)
{
  (void)in_sizes; (void)n_in; (void)out_size;
  const float* queries    = (const float*)d_in[0];
  const float* ref_points = (const float*)d_in[1];
  const float* value      = (const float*)d_in[2];
  // d_in[3] = value_spatial_shapes (int32) — compile-time constants here
  const float* V_W    = (const float*)d_in[4];
  const float* off_W  = (const float*)d_in[5];
  const float* off_b  = (const float*)d_in[6];
  const float* attn_W = (const float*)d_in[7];
  const float* attn_b = (const float*)d_in[8];
  const float* out_W  = (const float*)d_in[9];

  __half* v16 = (__half*)d_ws;
  const size_t vb_half = (size_t)H_ * VLEN_ * 32;        // halves per batch (= VLEN*256)

  if (ws_size >= (size_t)B_ * vb_half * sizeof(__half)) {
    // Batched path: one vproj launch (all batches), one fused launch (all batches).
    gemm_vproj<<<dim3(B_ * VROW_, 2), 256, 0, stream>>>(
        value, V_W, v16, (size_t)VLEN_ * K_, vb_half);
    fused_offattn_sample<<<B_ * QBLK_, 256, 0, stream>>>(
        queries, ref_points, off_W, off_b, attn_W, attn_b, v16, (float*)d_out,
        (size_t)Q_ * K_, (size_t)Q_ * 8, vb_half, (size_t)Q_ * 256);
  } else {
    // Fallback: workspace holds one batch only; serialize per batch.
    for (int b = 0; b < B_; ++b) {
      gemm_vproj<<<dim3(VROW_, 2), 256, 0, stream>>>(
          value + (size_t)b * VLEN_ * K_, V_W, v16, 0, 0);
      fused_offattn_sample<<<QBLK_, 256, 0, stream>>>(
          queries + (size_t)b * Q_ * K_, ref_points + (size_t)b * Q_ * 8,
          off_W, off_b, attn_W, attn_b, v16,
          (float*)d_out + (size_t)b * Q_ * 256, 0, 0, 0, 0);
    }
  }
  // Output projection, in place on d_out (race-free).
  gemm_out_inplace<<<(B_ * Q_) / 64, 256, 0, stream>>>((float*)d_out, out_W);
}

// Round 4
// 604.423 us; speedup vs baseline: 1.2695x; 1.2695x over previous
//
#include <hip/hip_runtime.h>
#include <hip/hip_fp16.h>
#include <cstdint>
#include <cstddef>

// Problem constants (hardcoded per reference setup_inputs)
#define B_    4
#define Q_    8192
#define E_    256
#define H_    8
#define L_    4
#define P_    4
#define HD_   32
#define VLEN_ 21760   // 128^2 + 64^2 + 32^2 + 16^2
#define K_    256
#define VROW_ 170     // 128-row tiles per batch in vproj (170*128 = 21760)
#define QBLK_ (Q_ / 16)      // 512 query-tiles per batch in fused

__device__ inline unsigned pk2(float a, float b) {
  __half2 h = __floats2half2_rn(a, b);
  union { __half2 h2; unsigned u; } cv; cv.h2 = h; return cv.u;
}

// ---------------- Kernel 1: value projection -> fp16, head-major ----------------
// v16[h][pix][c] (c in 0..31 halves) = sum_k value[pix][k] * V_W[h*32+c][k].
// 128x128 tile per block, 8x8 per-thread fragments split 4+4 (conflict-free).
__global__ __launch_bounds__(256)
void gemm_vproj(const float* __restrict__ A,      // value (batch 0 base)
                const float* __restrict__ W,      // V_W (256,256)
                __half* __restrict__ C16,         // v16
                size_t a_bstride, size_t c_bstride)  // c_bstride in halves
{
  // k-major chunk tiles: [kk][row], row-stride 132 floats:
  //  - 132*4 = 528 B, 16B-aligned rows (b128 ok)
  //  - 4 rows apart = 528 floats = 16 mod 32 banks -> staging writes 2-way (free)
  __shared__ float Ak[16][132];
  __shared__ float Wk[16][132];

  const int t  = threadIdx.x;
  const int tx = t & 15, ty = t >> 4;
  const int b  = blockIdx.x / VROW_;
  const int bm = blockIdx.x - b * VROW_;
  const int bn = blockIdx.y;               // 0..1 (two 128-col halves)

  A   += (size_t)b * a_bstride;
  C16 += (size_t)b * c_bstride;

  float acc[8][8] = {};   // row r: gm = bm*128+(r>>2)*64+ty*4+(r&3); col c: gn = bn*128+(c>>2)*64+tx*4+(c&3)

  for (int k0 = 0; k0 < K_; k0 += 16) {
    __syncthreads();
#pragma unroll
    for (int i2 = 0; i2 < 2; ++i2) {
      const int idx = t + 256 * i2;        // 0..511
      const int row = idx >> 2;            // 0..127
      const int kq4 = (idx & 3) * 4;
      const float4 va = *(const float4*)(A + (size_t)(bm * 128 + row) * K_ + k0 + kq4);
      Ak[kq4+0][row] = va.x; Ak[kq4+1][row] = va.y; Ak[kq4+2][row] = va.z; Ak[kq4+3][row] = va.w;
      const float4 vw = *(const float4*)(W + (size_t)(bn * 128 + row) * K_ + k0 + kq4);
      Wk[kq4+0][row] = vw.x; Wk[kq4+1][row] = vw.y; Wk[kq4+2][row] = vw.z; Wk[kq4+3][row] = vw.w;
    }
    __syncthreads();
#pragma unroll
    for (int kk = 0; kk < 16; ++kk) {
      const float4 a0 = *(const float4*)&Ak[kk][ty * 4];
      const float4 a1 = *(const float4*)&Ak[kk][64 + ty * 4];
      const float4 w0 = *(const float4*)&Wk[kk][tx * 4];
      const float4 w1 = *(const float4*)&Wk[kk][64 + tx * 4];
      const float av[8] = {a0.x, a0.y, a0.z, a0.w, a1.x, a1.y, a1.z, a1.w};
      const float wv[8] = {w0.x, w0.y, w0.z, w0.w, w1.x, w1.y, w1.z, w1.w};
#pragma unroll
      for (int r = 0; r < 8; ++r)
#pragma unroll
        for (int c = 0; c < 8; ++c)
          acc[r][c] += av[r] * wv[c];
    }
  }

  // epilogue: fp16 stores, head-major layout [h][pix][32]
#pragma unroll
  for (int r = 0; r < 8; ++r) {
    const int gm = bm * 128 + (r >> 2) * 64 + ty * 4 + (r & 3);
#pragma unroll
    for (int cg = 0; cg < 2; ++cg) {
      const int gn0 = bn * 128 + cg * 64 + tx * 4;     // 4 contiguous channels, within one head
      const int h  = gn0 >> 5;
      const int c0 = gn0 & 31;
      __half* dst = C16 + ((size_t)h * VLEN_ + gm) * 32 + c0;
      uint2 sv;
      sv.x = pk2(acc[r][cg * 4 + 0], acc[r][cg * 4 + 1]);
      sv.y = pk2(acc[r][cg * 4 + 2], acc[r][cg * 4 + 3]);
      *(uint2*)dst = sv;
    }
  }
}

// ---------------- Kernel 2: fused offsets/attn GEMM + softmax + sampling ----------------
// One block = 16 consecutive queries of one batch. LDS budget = exactly 40960 B
// (poolA 16KB + poolB 24KB) -> 4 blocks/CU. VGPR capped at 128 via launch_bounds.
// GEMM: thread owns cols {lane*4..+3} (offsets) + {256+lane*2,+1} (attn):
// one ds_read_b128 + one ds_read_b64 per k. Gather: u (query-of-pair) lives in
// thread space (t>>7); each thread does 4 taps x 4 corners of fp16 data with
// fp32 accumulate, reduced over the 4-way tap split via shuffles.
__global__ __launch_bounds__(256, 4)
void fused_offattn_sample(const float* __restrict__ queries,
                          const float* __restrict__ ref_points,
                          const float* __restrict__ off_W,
                          const float* __restrict__ off_b,
                          const float* __restrict__ attn_W,
                          const float* __restrict__ attn_b,
                          const __half* __restrict__ v16,
                          float* __restrict__ outpre,
                          size_t q_bstride, size_t r_bstride,
                          size_t v_bstride, size_t o_bstride)   // v_bstride in halves
{
  __shared__ __align__(16) float poolA[16 * 256];   // qs[16][256] | {s_idx4, s_w4}[2][128]
  __shared__ __align__(16) float poolB[16 * 384];   // wck[16][384] | {s_px,s_py,s_a}[16][128]

  float (*qs)[256]   = (float (*)[256])poolA;
  int4*   s_idx4     = (int4*)poolA;                 // [u*128 + g]
  float4* s_w4       = (float4*)(poolA + 2048);      // [u*128 + g]
  float (*wck)[384]  = (float (*)[384])poolB;
  float (*s_px)[128] = (float (*)[128])poolB;              // floats [0, 2048)
  float (*s_py)[128] = (float (*)[128])(poolB + 2048);
  float (*s_a)[128]  = (float (*)[128])(poolB + 4096);

  const int t     = threadIdx.x;
  const int lane  = t & 63;
  const int wv    = t >> 6;                // wave id: q rows {wv, wv+4, wv+8, wv+12}
  const int b     = blockIdx.x >> 9;       // batch (0 when grid is per-batch)
  const int qbase = (blockIdx.x & (QBLK_ - 1)) * 16;

  queries    += (size_t)b * q_bstride;
  ref_points += (size_t)b * r_bstride;
  outpre     += (size_t)b * o_bstride;
  const __half* v16b = v16 + (size_t)b * v_bstride;

  // ---- load query tile (one-time; write conflicts negligible)
  {
    const int r  = t >> 4;
    const int c0 = (t & 15) * 16;
    const float4* src = (const float4*)(queries + (size_t)(qbase + r) * K_ + c0);
    *(float4*)&qs[r][c0 + 0]  = src[0];
    *(float4*)&qs[r][c0 + 4]  = src[1];
    *(float4*)&qs[r][c0 + 8]  = src[2];
    *(float4*)&qs[r][c0 + 12] = src[3];
  }

  // ---- precompute weight-staging sources: 1536 float4 per chunk, 6 per thread
  const float* wsrc[6]; int wcol[6]; int wm4[6];
#pragma unroll
  for (int n = 0; n < 6; ++n) {
    const int e   = n * 256 + t;           // 0..1535
    const int col = e % 384;               // output column
    const int m   = e / 384;               // k-subgroup (0..3)
    wcol[n] = col; wm4[n] = m * 4;
    wsrc[n] = (col < 256 ? off_W + (size_t)col * K_
                         : attn_W + (size_t)(col - 256) * K_) + m * 4;
  }

  float acc0[4][4] = {};   // offset cols lane*4+j, q rows wv+4i
  float acc1[2][4] = {};   // attn cols 256+lane*2+u2

  for (int k0 = 0; k0 < K_; k0 += 16) {
    __syncthreads();
#pragma unroll
    for (int n = 0; n < 6; ++n) {
      const float4 v = *(const float4*)(wsrc[n] + k0);
      wck[wm4[n] + 0][wcol[n]] = v.x;
      wck[wm4[n] + 1][wcol[n]] = v.y;
      wck[wm4[n] + 2][wcol[n]] = v.z;
      wck[wm4[n] + 3][wcol[n]] = v.w;
    }
    __syncthreads();
#pragma unroll
    for (int kc = 0; kc < 4; ++kc) {
      const float4 qv0 = *(const float4*)&qs[wv +  0][k0 + kc * 4];
      const float4 qv1 = *(const float4*)&qs[wv +  4][k0 + kc * 4];
      const float4 qv2 = *(const float4*)&qs[wv +  8][k0 + kc * 4];
      const float4 qv3 = *(const float4*)&qs[wv + 12][k0 + kc * 4];
      const float* q0 = (const float*)&qv0; const float* q1 = (const float*)&qv1;
      const float* q2 = (const float*)&qv2; const float* q3 = (const float*)&qv3;
#pragma unroll
      for (int s = 0; s < 4; ++s) {
        const int kk = kc * 4 + s;
        const float4 w4 = *(const float4*)&wck[kk][lane * 4];
        const float2 w2 = *(const float2*)&wck[kk][256 + lane * 2];
        const float qk[4] = {q0[s], q1[s], q2[s], q3[s]};
#pragma unroll
        for (int i = 0; i < 4; ++i) {
          acc0[0][i] += w4.x * qk[i]; acc0[1][i] += w4.y * qk[i];
          acc0[2][i] += w4.z * qk[i]; acc0[3][i] += w4.w * qk[i];
          acc1[0][i] += w2.x * qk[i]; acc1[1][i] += w2.y * qk[i];
        }
      }
    }
  }
  __syncthreads();   // wck dead from here; poolB becomes s_px/s_py/s_a

  // ---- offsets epilogue: thread owns cols lane*4..+3 = taps lane*2, lane*2+1
  // (x,y pairs thread-local; refs read straight from global, L2-hot)
  {
    const int l  = (lane >> 1) & 3;
    const int Wl = 128 >> l;
    const float sc = 0.5f * (float)(Wl - 1);
#pragma unroll
    for (int i = 0; i < 4; ++i) {
      const int q = wv + 4 * i;
      const float rx = ref_points[(size_t)(qbase + q) * 8 + l * 2 + 0];
      const float ry = ref_points[(size_t)(qbase + q) * 8 + l * 2 + 1];
#pragma unroll
      for (int j2 = 0; j2 < 2; ++j2) {
        const int colx = lane * 4 + j2 * 2;
        const int tap  = lane * 2 + j2;           // h*16 + l*4 + p
        float lx = rx + tanhf(acc0[j2 * 2 + 0][i] + off_b[colx + 0]);  // OFFSET_SCALE=1
        float ly = ry + tanhf(acc0[j2 * 2 + 1][i] + off_b[colx + 1]);
        lx = fminf(fmaxf(lx, -1.f), 1.f);
        ly = fminf(fmaxf(ly, -1.f), 1.f);
        s_px[q][tap] = (lx + 1.f) * sc;
        s_py[q][tap] = (ly + 1.f) * sc;
      }
    }
  }

  // ---- attention epilogue: thread owns logits lane*2, lane*2+1; head group = 8 lanes
  {
    const float ab0 = attn_b[lane * 2], ab1 = attn_b[lane * 2 + 1];
#pragma unroll
    for (int i = 0; i < 4; ++i) {
      const int q = wv + 4 * i;
      const float l0 = acc1[0][i] + ab0;
      const float l1 = acc1[1][i] + ab1;
      float m = fmaxf(l0, l1);
#pragma unroll
      for (int msk = 1; msk < 8; msk <<= 1) m = fmaxf(m, __shfl_xor(m, msk));
      const float e0 = __expf(l0 - m), e1 = __expf(l1 - m);
      float s = e0 + e1;
#pragma unroll
      for (int msk = 1; msk < 8; msk <<= 1) s += __shfl_xor(s, msk);
      s_a[q][lane * 2 + 0] = e0 / s;
      s_a[q][lane * 2 + 1] = e1 / s;
    }
  }

  // ---- sampling: 8 query-pairs; u in thread space; fp16 gather, fp32 accumulate
  const int c4 = t & 3;                     // 16B channel group (8 fp16 ch)
  const int j3 = (t >> 2) & 3;              // tap-slot split (4 taps each)
  const int h  = ((t >> 6) & 1) * 4 + ((t >> 4) & 3);   // head
  const int u  = t >> 7;                    // query of the pair
  const float4* vb4 = (const float4*)v16b + (size_t)h * (VLEN_ * 4) + c4;  // slice = 4 float4

  for (int qp = 0; qp < 8; ++qp) {
    __syncthreads();              // s_idx4/s_w4 free (qs dead); orders epilogue (qp=0)
    {
      const int uu = t >> 7;      // which query of the pair
      const int g  = t & 127;     // tap index h*16 + l*4 + p
      const int qq = qp * 2 + uu;
      const float a = s_a[qq][g];
      const int l  = (g >> 2) & 3;
      const int Wl = 128 >> l;
      const int base = (l == 0) ? 0 : (l == 1) ? 16384 : (l == 2) ? 20480 : 21504;
      const float x = s_px[qq][g], y = s_py[qq][g];
      const float x0f = floorf(x), y0f = floorf(y);
      const float wx = x - x0f, wy = y - y0f;
      const int x0 = min(max((int)x0f, 0), Wl - 1);
      const int x1 = min(x0 + 1, Wl - 1);
      const int y0 = min(max((int)y0f, 0), Wl - 1);
      const int y1 = min(y0 + 1, Wl - 1);
      s_idx4[uu * 128 + g] = make_int4(base + y0 * Wl + x0, base + y0 * Wl + x1,
                                       base + y1 * Wl + x0, base + y1 * Wl + x1);
      s_w4[uu * 128 + g] = make_float4(a * (1.f - wy) * (1.f - wx), a * (1.f - wy) * wx,
                                       a * wy * (1.f - wx),          a * wy * wx);
    }
    __syncthreads();
    float o[8] = {0.f, 0.f, 0.f, 0.f, 0.f, 0.f, 0.f, 0.f};
#pragma unroll
    for (int jj = 0; jj < 4; ++jj) {
      const int g = h * 16 + jj * 4 + j3;
      const int4   id = s_idx4[u * 128 + g];
      const float4 w  = s_w4[u * 128 + g];
      const float4 r0 = vb4[(size_t)id.x * 4];
      const float4 r1 = vb4[(size_t)id.y * 4];
      const float4 r2 = vb4[(size_t)id.z * 4];
      const float4 r3 = vb4[(size_t)id.w * 4];
      const __half2* p0 = (const __half2*)&r0;
      const __half2* p1 = (const __half2*)&r1;
      const __half2* p2 = (const __half2*)&r2;
      const __half2* p3 = (const __half2*)&r3;
#pragma unroll
      for (int c = 0; c < 4; ++c) {
        o[2*c+0] += w.x * __low2float(p0[c])  + w.y * __low2float(p1[c])
                  + w.z * __low2float(p2[c])  + w.w * __low2float(p3[c]);
        o[2*c+1] += w.x * __high2float(p0[c]) + w.y * __high2float(p1[c])
                  + w.z * __high2float(p2[c]) + w.w * __high2float(p3[c]);
      }
    }
    // reduce over j3 (lanes ^4, ^8 share u, h, c4)
#pragma unroll
    for (int msk = 4; msk <= 8; msk <<= 1)
#pragma unroll
      for (int c = 0; c < 8; ++c) o[c] += __shfl_xor(o[c], msk);
    if (j3 == 0) {
      float* dst = outpre + (size_t)(qbase + qp * 2 + u) * 256 + h * 32 + c4 * 8;
      *(float4*)dst       = make_float4(o[0], o[1], o[2], o[3]);
      *(float4*)(dst + 4) = make_float4(o[4], o[5], o[6], o[7]);
    }
  }
}

// ---------------- Kernel 3: in-place output projection (fp32, race-free) ----------------
#define OSTEP(q, COMP) { \
  const float4 w = *(const float4*)&Wk[kc*4+(q)][tx*4]; \
  acc[0][0]+=a0.COMP*w.x; acc[0][1]+=a0.COMP*w.y; acc[0][2]+=a0.COMP*w.z; acc[0][3]+=a0.COMP*w.w; \
  acc[1][0]+=a1.COMP*w.x; acc[1][1]+=a1.COMP*w.y; acc[1][2]+=a1.COMP*w.z; acc[1][3]+=a1.COMP*w.w; \
  acc[2][0]+=a2.COMP*w.x; acc[2][1]+=a2.COMP*w.y; acc[2][2]+=a2.COMP*w.z; acc[2][3]+=a2.COMP*w.w; \
  acc[3][0]+=a3.COMP*w.x; acc[3][1]+=a3.COMP*w.y; acc[3][2]+=a3.COMP*w.z; acc[3][3]+=a3.COMP*w.w; }

__global__ __launch_bounds__(256)
void gemm_out_inplace(float* __restrict__ D,       // d_out (32768,256) fp32
                      const float* __restrict__ Wout)
{
  __shared__ float As[64][260];   // padded: stride 1040 B (16B-aligned, banks +4/row)
  __shared__ float Wk[16][68];    // k-major weight chunk

  const int t  = threadIdx.x;
  const int tx = t & 15, ty = t >> 4;
  const int bm = blockIdx.x;
  const int lr  = t >> 2;
  const int lc4 = (t & 3) * 4;

  // cache this block's 64 rows (16384 floats = 4096 float4)
#pragma unroll
  for (int i = 0; i < 16; ++i) {
    const int e = t + i * 256;               // float4 index 0..4095
    const int r = e >> 6, cc = e & 63;
    *(float4*)&As[r][cc * 4] = *(const float4*)(D + (size_t)(bm * 64 + r) * 256 + cc * 4);
  }

  for (int bn = 0; bn < 4; ++bn) {
    float acc[4][4] = {};
    for (int k0 = 0; k0 < K_; k0 += 16) {
      __syncthreads();   // protect Wk (and As on first iter) before rewrite
      {
        const float4 vw = *(const float4*)(Wout + (size_t)(bn * 64 + lr) * K_ + k0 + lc4);
        Wk[lc4+0][lr] = vw.x; Wk[lc4+1][lr] = vw.y; Wk[lc4+2][lr] = vw.z; Wk[lc4+3][lr] = vw.w;
      }
      __syncthreads();
#pragma unroll
      for (int kc = 0; kc < 4; ++kc) {
        const float4 a0 = *(const float4*)&As[ty * 4 + 0][k0 + kc * 4];
        const float4 a1 = *(const float4*)&As[ty * 4 + 1][k0 + kc * 4];
        const float4 a2 = *(const float4*)&As[ty * 4 + 2][k0 + kc * 4];
        const float4 a3 = *(const float4*)&As[ty * 4 + 3][k0 + kc * 4];
        OSTEP(0, x) OSTEP(1, y) OSTEP(2, z) OSTEP(3, w)
      }
    }
#pragma unroll
    for (int i = 0; i < 4; ++i)
#pragma unroll
      for (int j = 0; j < 4; ++j) {
        const int gm = bm * 64 + ty * 4 + i;
        const int gn = bn * 64 + tx * 4 + j;
        D[(size_t)gm * 256 + gn] = acc[i][j];    // own rows; As is a private copy
      }
  }
}

extern "C" void kernel_launch(void* const* d_in, const int* in_sizes, int n_in,
                              void* d_out, int out_size, void* d_ws, size_t ws_size,
                              hipStream_t stream)
{
  (void)in_sizes; (void)n_in; (void)out_size;
  const float* queries    = (const float*)d_in[0];
  const float* ref_points = (const float*)d_in[1];
  const float* value      = (const float*)d_in[2];
  // d_in[3] = value_spatial_shapes (int32) — compile-time constants here
  const float* V_W    = (const float*)d_in[4];
  const float* off_W  = (const float*)d_in[5];
  const float* off_b  = (const float*)d_in[6];
  const float* attn_W = (const float*)d_in[7];
  const float* attn_b = (const float*)d_in[8];
  const float* out_W  = (const float*)d_in[9];

  __half* v16 = (__half*)d_ws;
  const size_t vb_half = (size_t)H_ * VLEN_ * 32;        // halves per batch (= VLEN*256)

  if (ws_size >= (size_t)B_ * vb_half * sizeof(__half)) {
    // Batched path: one vproj launch (all batches), one fused launch (all batches).
    gemm_vproj<<<dim3(B_ * VROW_, 2), 256, 0, stream>>>(
        value, V_W, v16, (size_t)VLEN_ * K_, vb_half);
    fused_offattn_sample<<<B_ * QBLK_, 256, 0, stream>>>(
        queries, ref_points, off_W, off_b, attn_W, attn_b, v16, (float*)d_out,
        (size_t)Q_ * K_, (size_t)Q_ * 8, vb_half, (size_t)Q_ * 256);
  } else {
    // Fallback: workspace holds one batch only; serialize per batch.
    for (int b = 0; b < B_; ++b) {
      gemm_vproj<<<dim3(VROW_, 2), 256, 0, stream>>>(
          value + (size_t)b * VLEN_ * K_, V_W, v16, 0, 0);
      fused_offattn_sample<<<QBLK_, 256, 0, stream>>>(
          queries + (size_t)b * Q_ * K_, ref_points + (size_t)b * Q_ * 8,
          off_W, off_b, attn_W, attn_b, v16,
          (float*)d_out + (size_t)b * Q_ * 256, 0, 0, 0, 0);
    }
  }
  // Output projection, in place on d_out (race-free).
  gemm_out_inplace<<<(B_ * Q_) / 64, 256, 0, stream>>>((float*)d_out, out_W);
}